// Round 1
// baseline (41302.917 us; speedup 1.0000x reference)
//
#include <hip/hip_runtime.h>
#include <hip/hip_cooperative_groups.h>

namespace cg = cooperative_groups;

#define T_SEQ 512
#define BATCH 64
#define HDIM 1024
#define G4H 4096
#define TBROWS (T_SEQ * BATCH)   // 32768

using short8  = __attribute__((ext_vector_type(8))) short;   // 8 bf16 (4 VGPRs)
using float4v = __attribute__((ext_vector_type(4))) float;   // MFMA C/D

__device__ __forceinline__ unsigned short f2bf(float f) {
    union { float f; unsigned int u; } v; v.f = f;
    return (unsigned short)((v.u + 0x7fffu + ((v.u >> 16) & 1u)) >> 16); // RNE
}
__device__ __forceinline__ float bf2f(unsigned short b) {
    union { unsigned int u; float f; } v; v.u = ((unsigned int)b) << 16;
    return v.f;
}

// ---------------- fp32 -> bf16 bulk convert ----------------
__global__ void k_cvt(const float* __restrict__ src, unsigned short* __restrict__ dst, int n) {
    int i = (blockIdx.x * 256 + threadIdx.x) * 4;
    if (i >= n) return;                 // n % 4 == 0 for all our uses
    float4 v = *(const float4*)(src + i);
    ushort4 o;
    o.x = f2bf(v.x); o.y = f2bf(v.y); o.z = f2bf(v.z); o.w = f2bf(v.w);
    *(ushort4*)(dst + i) = o;
}

__global__ void k_bias(const float* __restrict__ a0, const float* __restrict__ b0,
                       const float* __restrict__ a1, const float* __restrict__ b1,
                       float* __restrict__ s0, float* __restrict__ s1) {
    int t = blockIdx.x * 256 + threadIdx.x;
    if (t < G4H) s0[t] = a0[t] + b0[t];
    else if (t < 2 * G4H) s1[t - G4H] = a1[t - G4H] + b1[t - G4H];
}

// ---------------- bf16 MFMA GEMM: C[M,N] = A[M,K] * B[N,K]^T + bias ----------------
// 128x128 tile, 4 waves (each 64x64 = 4x4 MFMA 16x16x32 tiles), BK=64,
// global_load_lds width 16, XOR-swizzled 16B chunks for dense ds_read_b128.
__global__ __launch_bounds__(256) void k_gemm_bt(
    const unsigned short* __restrict__ A,
    const unsigned short* __restrict__ B,
    const float* __restrict__ bias,
    unsigned short* __restrict__ C,     // bf16 output
    int M, int N, int K)
{
    __shared__ __align__(16) unsigned short Asm[128 * 64];
    __shared__ __align__(16) unsigned short Bsm[128 * 64];

    const int w    = threadIdx.x >> 6;
    const int lane = threadIdx.x & 63;
    const int q    = lane >> 4, r15 = lane & 15;
    const int m0   = blockIdx.y * 128;
    const int n0   = blockIdx.x * 128;
    const int wm   = w & 1, wn = w >> 1;

    float4v acc[4][4];
#pragma unroll
    for (int i = 0; i < 4; i++)
#pragma unroll
        for (int j = 0; j < 4; j++) acc[i][j] = (float4v){0.f, 0.f, 0.f, 0.f};

    for (int k0 = 0; k0 < K; k0 += 64) {
        __syncthreads();   // protect LDS from previous iteration's readers
#pragma unroll
        for (int ii = 0; ii < 4; ii++) {
            // physical LDS chunk index this lane fills; fetch the swizzled global chunk
            int plin = (ii * 4 + w) * 64 + lane;           // 0..1023
            int row  = plin >> 3;                          // tile row 0..127
            int gch  = (plin & 7) ^ (row & 7);             // global 8-elem chunk within BK
            const unsigned short* ga = A + (size_t)(m0 + row) * K + (k0 + gch * 8);
            const unsigned short* gb = B + (size_t)(n0 + row) * K + (k0 + gch * 8);
            __builtin_amdgcn_global_load_lds((const __attribute__((address_space(1))) void*)ga,
                                             (__attribute__((address_space(3))) void*)(Asm + plin * 8),
                                             16, 0, 0);
            __builtin_amdgcn_global_load_lds((const __attribute__((address_space(1))) void*)gb,
                                             (__attribute__((address_space(3))) void*)(Bsm + plin * 8),
                                             16, 0, 0);
        }
        __syncthreads();   // compiler drains vmcnt before barrier
#pragma unroll
        for (int kh = 0; kh < 2; kh++) {
            short8 af[4], bfr[4];
#pragma unroll
            for (int mi = 0; mi < 4; mi++) {
                int row = wm * 64 + mi * 16 + r15;
                int ch  = (kh * 4 + q) ^ (row & 7);
                af[mi]  = *(const short8*)(Asm + (row * 8 + ch) * 8);
            }
#pragma unroll
            for (int ni = 0; ni < 4; ni++) {
                int row = wn * 64 + ni * 16 + r15;
                int ch  = (kh * 4 + q) ^ (row & 7);
                bfr[ni] = *(const short8*)(Bsm + (row * 8 + ch) * 8);
            }
#pragma unroll
            for (int mi = 0; mi < 4; mi++)
#pragma unroll
                for (int ni = 0; ni < 4; ni++)
                    acc[mi][ni] = __builtin_amdgcn_mfma_f32_16x16x32_bf16(af[mi], bfr[ni], acc[mi][ni], 0, 0, 0);
        }
    }

    // epilogue: D row=(q*4+rr) col=r15 within each 16x16 tile (verified m89 layout)
#pragma unroll
    for (int ni = 0; ni < 4; ni++) {
        int col  = n0 + wn * 64 + ni * 16 + r15;
        float bv = bias[col];
#pragma unroll
        for (int mi = 0; mi < 4; mi++) {
            int rowb = m0 + wm * 64 + mi * 16 + q * 4;
#pragma unroll
            for (int rr = 0; rr < 4; rr++)
                C[(size_t)(rowb + rr) * N + col] = f2bf(acc[mi][ni][rr] + bv);
        }
    }
}

// ---------------- persistent LSTM recurrence (one launch per layer) ----------------
// 256 blocks x 256 threads; block nb owns hidden units [4nb,4nb+4) -> 16 W_hh rows
// (j = gate*4 + unit) staged in LDS as bf16 hi/lo in exact B-fragment order.
// h kept double-buffered in ws as bf16 hi/lo; 3-product MFMA ~= fp32 accuracy.
__global__ __launch_bounds__(256) void k_lstm(
    const float* __restrict__ Whh,            // [4096][1024] fp32 (from d_in)
    const unsigned short* __restrict__ xproj, // [T*B][4096] bf16
    unsigned short* __restrict__ h_hi,        // [2][B][H] bf16
    unsigned short* __restrict__ h_lo,        // [2][B][H] bf16
    unsigned short* __restrict__ out_b,       // layer0: bf16 h -> layer1 GEMM input (or null)
    float* __restrict__ out_f,                // layer1: fp32 h -> d_out (or null)
    float* __restrict__ hn, float* __restrict__ cn)
{
    extern __shared__ char smem[];
    unsigned short* Whi = (unsigned short*)smem;        // 16 rows * 1024 k  (32 KB)
    unsigned short* Wlo = Whi + 16 * HDIM;              // 32 KB
    float* glds         = (float*)(Wlo + 16 * HDIM);    // [64][17] gates (pad +1)

    const int nb   = blockIdx.x;
    const int tid  = threadIdx.x;
    const int w    = tid >> 6;
    const int lane = tid & 63;
    const int q    = lane >> 4, r15 = lane & 15;

    // ---- stage W_hh slice, fp32 -> bf16 hi/lo, fragment-order layout ----
    {
        int j  = tid >> 4;                 // 0..15 : j = gate*4 + unit
        int g  = j >> 2, ui = j & 3;
        size_t grow = (size_t)(g * HDIM + nb * 4 + ui) * HDIM;
        int kbase = (tid & 15) * 64;
#pragma unroll 8
        for (int e = 0; e < 64; e++) {
            int k = kbase + e;
            float wv = Whh[grow + k];
            unsigned short hi = f2bf(wv);
            unsigned short lo = f2bf(wv - bf2f(hi));
            int addr = ((k >> 3) * 16 + j) * 8 + (k & 7);  // [k/8][j][k%8]
            Whi[addr] = hi;
            Wlo[addr] = lo;
        }
    }

    cg::grid_group grid = cg::this_grid();
    float c_reg = 0.f;
    const int b_act = tid >> 2, ui_act = tid & 3;      // thread -> (batch, unit)
    const int u_glob = nb * 4 + ui_act;

    __syncthreads();

    for (int t = 0; t < T_SEQ; t++) {
        const int cur = t & 1, nxt = cur ^ 1;
        float4v a0 = (float4v){0.f,0.f,0.f,0.f};
        float4v a1 = a0, a2 = a0;
        if (t > 0) {
            // wave w handles batch rows [16w,16w+16); A-frag: m=lane&15, k=q*8+j
            const unsigned short* hhp = h_hi + cur * (BATCH * HDIM) + (size_t)(w * 16 + r15) * HDIM + q * 8;
            const unsigned short* hlp = h_lo + cur * (BATCH * HDIM) + (size_t)(w * 16 + r15) * HDIM + q * 8;
            const unsigned short* wbh = Whi + (q * 16 + r15) * 8;
            const unsigned short* wbl = Wlo + (q * 16 + r15) * 8;
#pragma unroll 4
            for (int kc = 0; kc < 32; kc++) {
                short8 ah = *(const short8*)(hhp + kc * 32);
                short8 al = *(const short8*)(hlp + kc * 32);
                short8 bh = *(const short8*)(wbh + kc * 512);
                short8 bl = *(const short8*)(wbl + kc * 512);
                a0 = __builtin_amdgcn_mfma_f32_16x16x32_bf16(ah, bh, a0, 0, 0, 0);
                a1 = __builtin_amdgcn_mfma_f32_16x16x32_bf16(al, bh, a1, 0, 0, 0);
                a2 = __builtin_amdgcn_mfma_f32_16x16x32_bf16(ah, bl, a2, 0, 0, 0);
            }
        }
        {   // gates -> LDS: D row=(q*4+rr) -> batch, col=r15 -> j
            int brow = w * 16 + q * 4;
#pragma unroll
            for (int rr = 0; rr < 4; rr++)
                glds[(brow + rr) * 17 + r15] = a0[rr] + a1[rr] + a2[rr];
        }
        __syncthreads();
        {   // activations: one thread per (batch, unit)
            const unsigned short* xp = xproj + (size_t)(t * BATCH + b_act) * G4H + u_glob;
            float gi = glds[b_act * 17 +  0 + ui_act] + bf2f(xp[0]);
            float gf = glds[b_act * 17 +  4 + ui_act] + bf2f(xp[1024]);
            float gg = glds[b_act * 17 +  8 + ui_act] + bf2f(xp[2048]);
            float go = glds[b_act * 17 + 12 + ui_act] + bf2f(xp[3072]);
            float si = 1.f / (1.f + expf(-gi));
            float sf = 1.f / (1.f + expf(-gf));
            float so = 1.f / (1.f + expf(-go));
            float tg = tanhf(gg);
            c_reg = sf * c_reg + si * tg;
            float hv = so * tanhf(c_reg);
            unsigned short hb = f2bf(hv);
            int hoff = nxt * (BATCH * HDIM) + b_act * HDIM + u_glob;
            h_hi[hoff] = hb;
            h_lo[hoff] = f2bf(hv - bf2f(hb));
            size_t ooff = (size_t)(t * BATCH + b_act) * HDIM + u_glob;
            if (out_b) out_b[ooff] = hb;
            if (out_f) out_f[ooff] = hv;
            if (t == T_SEQ - 1) {
                hn[b_act * HDIM + u_glob] = hv;
                cn[b_act * HDIM + u_glob] = c_reg;
            }
        }
        grid.sync();   // publishes h (device-scope) + subsumes block barrier
    }
}

extern "C" void kernel_launch(void* const* d_in, const int* in_sizes, int n_in,
                              void* d_out, int out_size, void* d_ws, size_t ws_size,
                              hipStream_t stream) {
    (void)in_sizes; (void)n_in; (void)out_size; (void)ws_size;
    const float* x    = (const float*)d_in[0];
    const float* Wih0 = (const float*)d_in[1];
    const float* Whh0 = (const float*)d_in[2];
    const float* bih0 = (const float*)d_in[3];
    const float* bhh0 = (const float*)d_in[4];
    const float* Wih1 = (const float*)d_in[5];
    const float* Whh1 = (const float*)d_in[6];
    const float* bih1 = (const float*)d_in[7];
    const float* bhh1 = (const float*)d_in[8];
    float* out = (float*)d_out;

    // ---- workspace layout (~420 MB) ----
    unsigned short* xb0   = (unsigned short*)d_ws;                 // x bf16        [TB][1024]
    unsigned short* xb1   = xb0 + (size_t)TBROWS * HDIM;           // layer0 h bf16 [TB][1024]
    unsigned short* wb0   = xb1 + (size_t)TBROWS * HDIM;           // W_ih0 bf16
    unsigned short* wb1   = wb0 + (size_t)G4H * HDIM;              // W_ih1 bf16
    unsigned short* xproj = wb1 + (size_t)G4H * HDIM;              // x_proj bf16 [TB][4096] (reused)
    unsigned short* hhi   = xproj + (size_t)TBROWS * G4H;          // h hi [2][B][H]
    unsigned short* hlo   = hhi + 2 * BATCH * HDIM;                // h lo [2][B][H]
    float* bsum0          = (float*)(hlo + 2 * BATCH * HDIM);      // b_ih+b_hh
    float* bsum1          = bsum0 + G4H;

    float* hn0 = out + (size_t)TBROWS * HDIM;   // h_n[0]
    float* hn1 = hn0 + BATCH * HDIM;            // h_n[1]
    float* cn0 = hn1 + BATCH * HDIM;            // c_n[0]
    float* cn1 = cn0 + BATCH * HDIM;            // c_n[1]

    const unsigned lstm_lds = 16 * HDIM * 2 * 2 + 64 * 17 * 4;  // 69888 B

    // conversions
    k_cvt<<<(TBROWS * HDIM / 4 + 255) / 256, 256, 0, stream>>>(x, xb0, TBROWS * HDIM);
    k_cvt<<<(G4H * HDIM / 4 + 255) / 256, 256, 0, stream>>>(Wih0, wb0, G4H * HDIM);
    k_cvt<<<(G4H * HDIM / 4 + 255) / 256, 256, 0, stream>>>(Wih1, wb1, G4H * HDIM);
    k_bias<<<(2 * G4H + 255) / 256, 256, 0, stream>>>(bih0, bhh0, bih1, bhh1, bsum0, bsum1);

    dim3 gg(G4H / 128, TBROWS / 128);   // 32 x 256 blocks

    // layer 0
    k_gemm_bt<<<gg, 256, 0, stream>>>(xb0, wb0, bsum0, xproj, TBROWS, G4H, HDIM);
    {
        const float* whh = Whh0;
        const unsigned short* xp = xproj;
        unsigned short* hh = hhi; unsigned short* hl = hlo;
        unsigned short* ob = xb1;
        float* of = nullptr;
        float* hn = hn0; float* cn = cn0;
        void* args[] = {(void*)&whh, (void*)&xp, (void*)&hh, (void*)&hl,
                        (void*)&ob, (void*)&of, (void*)&hn, (void*)&cn};
        hipLaunchCooperativeKernel((void*)k_lstm, dim3(256), dim3(256), args, lstm_lds, stream);
    }

    // layer 1
    k_gemm_bt<<<gg, 256, 0, stream>>>(xb1, wb1, bsum1, xproj, TBROWS, G4H, HDIM);
    {
        const float* whh = Whh1;
        const unsigned short* xp = xproj;
        unsigned short* hh = hhi; unsigned short* hl = hlo;
        unsigned short* ob = nullptr;
        float* of = out;
        float* hn = hn1; float* cn = cn1;
        void* args[] = {(void*)&whh, (void*)&xp, (void*)&hh, (void*)&hl,
                        (void*)&ob, (void*)&of, (void*)&hn, (void*)&cn};
        hipLaunchCooperativeKernel((void*)k_lstm, dim3(256), dim3(256), args, lstm_lds, stream);
    }
}

// Round 2
// 21587.958 us; speedup vs baseline: 1.9132x; 1.9132x over previous
//
#include <hip/hip_runtime.h>
#include <hip/hip_cooperative_groups.h>

#define T_SEQ 512
#define BATCH 64
#define HDIM 1024
#define G4H 4096
#define TBROWS (T_SEQ * BATCH)   // 32768
#define NBLK 128                 // recurrence blocks
#define UPB 8                    // hidden units per block
#define CNT_STRIDE 16            // u32s between step counters (64B)

using short8  = __attribute__((ext_vector_type(8))) short;   // 8 bf16 (4 VGPRs)
using float4v = __attribute__((ext_vector_type(4))) float;   // MFMA C/D

__device__ __forceinline__ unsigned short f2bf(float f) {
    union { float f; unsigned int u; } v; v.f = f;
    return (unsigned short)((v.u + 0x7fffu + ((v.u >> 16) & 1u)) >> 16); // RNE
}
__device__ __forceinline__ float bf2f(unsigned short b) {
    union { unsigned int u; float f; } v; v.u = ((unsigned int)b) << 16;
    return v.f;
}

// ---------------- fp32 -> bf16 bulk convert ----------------
__global__ void k_cvt(const float* __restrict__ src, unsigned short* __restrict__ dst, int n) {
    int i = (blockIdx.x * 256 + threadIdx.x) * 4;
    if (i >= n) return;                 // n % 4 == 0 for all our uses
    float4 v = *(const float4*)(src + i);
    ushort4 o;
    o.x = f2bf(v.x); o.y = f2bf(v.y); o.z = f2bf(v.z); o.w = f2bf(v.w);
    *(ushort4*)(dst + i) = o;
}

__global__ void k_bias(const float* __restrict__ a0, const float* __restrict__ b0,
                       const float* __restrict__ a1, const float* __restrict__ b1,
                       float* __restrict__ s0, float* __restrict__ s1) {
    int t = blockIdx.x * 256 + threadIdx.x;
    if (t < G4H) s0[t] = a0[t] + b0[t];
    else if (t < 2 * G4H) s1[t - G4H] = a1[t - G4H] + b1[t - G4H];
}

// ---------------- bf16 MFMA GEMM: C[M,N] = A[M,K] * B[N,K]^T + bias ----------------
// (unchanged from R1 — not the bottleneck; 128x128 tile, global_load_lds w16, XOR swizzle)
__global__ __launch_bounds__(256) void k_gemm_bt(
    const unsigned short* __restrict__ A,
    const unsigned short* __restrict__ B,
    const float* __restrict__ bias,
    unsigned short* __restrict__ C,
    int M, int N, int K)
{
    __shared__ __align__(16) unsigned short Asm[128 * 64];
    __shared__ __align__(16) unsigned short Bsm[128 * 64];

    const int w    = threadIdx.x >> 6;
    const int lane = threadIdx.x & 63;
    const int q    = lane >> 4, r15 = lane & 15;
    const int m0   = blockIdx.y * 128;
    const int n0   = blockIdx.x * 128;
    const int wm   = w & 1, wn = w >> 1;

    float4v acc[4][4];
#pragma unroll
    for (int i = 0; i < 4; i++)
#pragma unroll
        for (int j = 0; j < 4; j++) acc[i][j] = (float4v){0.f, 0.f, 0.f, 0.f};

    for (int k0 = 0; k0 < K; k0 += 64) {
        __syncthreads();
#pragma unroll
        for (int ii = 0; ii < 4; ii++) {
            int plin = (ii * 4 + w) * 64 + lane;
            int row  = plin >> 3;
            int gch  = (plin & 7) ^ (row & 7);
            const unsigned short* ga = A + (size_t)(m0 + row) * K + (k0 + gch * 8);
            const unsigned short* gb = B + (size_t)(n0 + row) * K + (k0 + gch * 8);
            __builtin_amdgcn_global_load_lds((const __attribute__((address_space(1))) void*)ga,
                                             (__attribute__((address_space(3))) void*)(Asm + plin * 8),
                                             16, 0, 0);
            __builtin_amdgcn_global_load_lds((const __attribute__((address_space(1))) void*)gb,
                                             (__attribute__((address_space(3))) void*)(Bsm + plin * 8),
                                             16, 0, 0);
        }
        __syncthreads();
#pragma unroll
        for (int kh = 0; kh < 2; kh++) {
            short8 af[4], bfr[4];
#pragma unroll
            for (int mi = 0; mi < 4; mi++) {
                int row = wm * 64 + mi * 16 + r15;
                int ch  = (kh * 4 + q) ^ (row & 7);
                af[mi]  = *(const short8*)(Asm + (row * 8 + ch) * 8);
            }
#pragma unroll
            for (int ni = 0; ni < 4; ni++) {
                int row = wn * 64 + ni * 16 + r15;
                int ch  = (kh * 4 + q) ^ (row & 7);
                bfr[ni] = *(const short8*)(Bsm + (row * 8 + ch) * 8);
            }
#pragma unroll
            for (int mi = 0; mi < 4; mi++)
#pragma unroll
                for (int ni = 0; ni < 4; ni++)
                    acc[mi][ni] = __builtin_amdgcn_mfma_f32_16x16x32_bf16(af[mi], bfr[ni], acc[mi][ni], 0, 0, 0);
        }
    }

#pragma unroll
    for (int ni = 0; ni < 4; ni++) {
        int col  = n0 + wn * 64 + ni * 16 + r15;
        float bv = bias[col];
#pragma unroll
        for (int mi = 0; mi < 4; mi++) {
            int rowb = m0 + wm * 64 + mi * 16 + q * 4;
#pragma unroll
            for (int rr = 0; rr < 4; rr++)
                C[(size_t)(rowb + rr) * N + col] = f2bf(acc[mi][ni][rr] + bv);
        }
    }
}

// ---------------- persistent LSTM recurrence ----------------
// 128 blocks x 256 threads; block nb owns units [8nb, 8nb+8) -> 32 W_hh gate-rows
// (j = gate*8 + unit), staged in LDS bf16 hi/lo in B-fragment order, split into
// two j-groups of 16. Custom per-step counter barrier replaces cg::grid.sync().
__global__ __launch_bounds__(256) void k_lstm(
    const float* __restrict__ Whh,            // [4096][1024] fp32
    const unsigned short* __restrict__ xproj, // [T*B][4096] bf16 (bias included)
    unsigned short* __restrict__ h_hi,        // [2][B][H] bf16
    unsigned short* __restrict__ h_lo,        // [2][B][H] bf16
    unsigned short* __restrict__ out_b,       // layer0: bf16 h for layer-1 GEMM (or null)
    float* __restrict__ out_f,                // layer1: fp32 h -> d_out (or null)
    float* __restrict__ hn, float* __restrict__ cn,
    unsigned* __restrict__ bar,               // step counters, CNT_STRIDE u32 apart
    int bar_base)                             // 0 for layer0, T_SEQ for layer1
{
    extern __shared__ char smem[];
    unsigned short* Whi = (unsigned short*)smem;        // [2 jg][128 kgran][16 j][8]  64 KB
    unsigned short* Wlo = Whi + 32 * HDIM;              // 64 KB
    float* glds         = (float*)(Wlo + 32 * HDIM);    // [64][33] gates (pad)

    const int nb   = blockIdx.x;
    const int tid  = threadIdx.x;
    const int w    = tid >> 6;
    const int lane = tid & 63;
    const int q    = lane >> 4, r15 = lane & 15;

    // ---- stage W_hh slice: fp32 -> bf16 hi/lo, B-fragment order ----
    {
        int j    = tid >> 3;              // 0..31, j = gate*8 + unit
        int g    = j >> 3, ui = j & 7;
        int jg   = j >> 4, jloc = j & 15;
        size_t grow = (size_t)(g * HDIM + nb * UPB + ui) * HDIM;
        unsigned short* whiB = Whi + jg * 16 * HDIM;
        unsigned short* wloB = Wlo + jg * 16 * HDIM;
        int kbase = (tid & 7) * 128;
        for (int e = 0; e < 128; e += 4) {
            int k = kbase + e;
            float4 wv = *(const float4*)(Whh + grow + k);
            ushort4 hi4, lo4;
            float vv[4] = {wv.x, wv.y, wv.z, wv.w};
            unsigned short hs[4], ls[4];
#pragma unroll
            for (int m = 0; m < 4; m++) {
                hs[m] = f2bf(vv[m]);
                ls[m] = f2bf(vv[m] - bf2f(hs[m]));
            }
            hi4 = (ushort4){hs[0], hs[1], hs[2], hs[3]};
            lo4 = (ushort4){ls[0], ls[1], ls[2], ls[3]};
            int addr = (k >> 3) * 128 + jloc * 8 + (k & 7);   // shorts
            *(ushort4*)(whiB + addr) = hi4;
            *(ushort4*)(wloB + addr) = lo4;
        }
    }

    const int b_act = tid >> 2;                 // batch row for activation
    const int up    = tid & 3;                  // unit pair
    const int u0    = up * 2;                   // local units u0, u0+1
    float c0 = 0.f, c1 = 0.f;

    __syncthreads();

    for (int t = 0; t < T_SEQ; t++) {
        const int cur = t & 1, nxt = cur ^ 1;

        // ---- prefetch xproj for this step (independent of h; hides under MFMA) ----
        ushort2 xpv[4];
        {
            const unsigned short* xpb = xproj + ((size_t)t * BATCH + b_act) * G4H + nb * UPB + u0;
#pragma unroll
            for (int g = 0; g < 4; g++) xpv[g] = *(const ushort2*)(xpb + g * HDIM);
        }

        // ---- recurrent GEMM: gates[b][j] += h_t . W_hh[j] (hi/lo 3-product) ----
        float4v acc[2][3];
#pragma unroll
        for (int jg = 0; jg < 2; jg++)
#pragma unroll
            for (int p = 0; p < 3; p++) acc[jg][p] = (float4v){0.f, 0.f, 0.f, 0.f};

        if (t > 0) {
            const unsigned short* hr = h_hi + cur * (BATCH * HDIM) + (size_t)(w * 16 + r15) * HDIM + q * 8;
            const unsigned short* lr = h_lo + cur * (BATCH * HDIM) + (size_t)(w * 16 + r15) * HDIM + q * 8;
#pragma unroll 4
            for (int kc = 0; kc < 32; kc++) {
                short8 ah = *(const short8*)(hr + kc * 32);
                short8 al = *(const short8*)(lr + kc * 32);
#pragma unroll
                for (int jg = 0; jg < 2; jg++) {
                    const unsigned short* bb = Whi + jg * 16 * HDIM + (kc * 4 + q) * 128 + r15 * 8;
                    const unsigned short* bl = Wlo + jg * 16 * HDIM + (kc * 4 + q) * 128 + r15 * 8;
                    short8 bh = *(const short8*)bb;
                    short8 blv = *(const short8*)bl;
                    acc[jg][0] = __builtin_amdgcn_mfma_f32_16x16x32_bf16(ah, bh,  acc[jg][0], 0, 0, 0);
                    acc[jg][1] = __builtin_amdgcn_mfma_f32_16x16x32_bf16(al, bh,  acc[jg][1], 0, 0, 0);
                    acc[jg][2] = __builtin_amdgcn_mfma_f32_16x16x32_bf16(ah, blv, acc[jg][2], 0, 0, 0);
                }
            }
        }

        // gates -> LDS: D row=(q*4+rr) -> batch, col=r15 -> j within group
#pragma unroll
        for (int jg = 0; jg < 2; jg++) {
            int brow = w * 16 + q * 4;
#pragma unroll
            for (int rr = 0; rr < 4; rr++)
                glds[(brow + rr) * 33 + jg * 16 + r15] = acc[jg][0][rr] + acc[jg][1][rr] + acc[jg][2][rr];
        }
        __syncthreads();

        // ---- activations: thread -> (batch b_act, units u0,u0+1) ----
        {
            const float* gr = glds + b_act * 33;
            float gi0 = gr[0*8 + u0]     + bf2f(xpv[0].x);
            float gi1 = gr[0*8 + u0 + 1] + bf2f(xpv[0].y);
            float gf0 = gr[1*8 + u0]     + bf2f(xpv[1].x);
            float gf1 = gr[1*8 + u0 + 1] + bf2f(xpv[1].y);
            float gg0 = gr[2*8 + u0]     + bf2f(xpv[2].x);
            float gg1 = gr[2*8 + u0 + 1] + bf2f(xpv[2].y);
            float go0 = gr[3*8 + u0]     + bf2f(xpv[3].x);
            float go1 = gr[3*8 + u0 + 1] + bf2f(xpv[3].y);

            c0 = (1.f / (1.f + __expf(-gf0))) * c0 + (1.f / (1.f + __expf(-gi0))) * tanhf(gg0);
            c1 = (1.f / (1.f + __expf(-gf1))) * c1 + (1.f / (1.f + __expf(-gi1))) * tanhf(gg1);
            float hv0 = (1.f / (1.f + __expf(-go0))) * tanhf(c0);
            float hv1 = (1.f / (1.f + __expf(-go1))) * tanhf(c1);

            unsigned short hb0 = f2bf(hv0), hb1 = f2bf(hv1);
            int hidx = b_act * HDIM + nb * UPB + u0;
            *(ushort2*)(h_hi + nxt * (BATCH * HDIM) + hidx) = (ushort2){hb0, hb1};
            *(ushort2*)(h_lo + nxt * (BATCH * HDIM) + hidx) =
                (ushort2){f2bf(hv0 - bf2f(hb0)), f2bf(hv1 - bf2f(hb1))};

            size_t ooff = ((size_t)t * BATCH + b_act) * HDIM + nb * UPB + u0;
            if (out_b) *(ushort2*)(out_b + ooff) = (ushort2){hb0, hb1};
            if (out_f) *(float2*)(out_f + ooff) = (float2){hv0, hv1};
            if (t == T_SEQ - 1) {
                hn[hidx] = hv0; hn[hidx + 1] = hv1;
                cn[hidx] = c0;  cn[hidx + 1] = c1;
            }
        }

        // ---- custom grid barrier: per-step counter, thread-0 arrival ----
        __syncthreads();   // drains all waves' h stores to L2 (vmcnt(0) before s_barrier)
        if (tid == 0) {
            unsigned* c = bar + (size_t)(bar_base + t) * CNT_STRIDE;
            __threadfence();   // agent release: L2 writeback across XCDs
            __hip_atomic_fetch_add(c, 1u, __ATOMIC_RELAXED, __HIP_MEMORY_SCOPE_AGENT);
            while (__hip_atomic_load(c, __ATOMIC_RELAXED, __HIP_MEMORY_SCOPE_AGENT) < (unsigned)NBLK)
                __builtin_amdgcn_s_sleep(1);
            __threadfence();   // agent acquire: invalidate L1/L2 before reading new h
        }
        __syncthreads();
    }
}

extern "C" void kernel_launch(void* const* d_in, const int* in_sizes, int n_in,
                              void* d_out, int out_size, void* d_ws, size_t ws_size,
                              hipStream_t stream) {
    (void)in_sizes; (void)n_in; (void)out_size; (void)ws_size;
    const float* x    = (const float*)d_in[0];
    const float* Wih0 = (const float*)d_in[1];
    const float* Whh0 = (const float*)d_in[2];
    const float* bih0 = (const float*)d_in[3];
    const float* bhh0 = (const float*)d_in[4];
    const float* Wih1 = (const float*)d_in[5];
    const float* Whh1 = (const float*)d_in[6];
    const float* bih1 = (const float*)d_in[7];
    const float* bhh1 = (const float*)d_in[8];
    float* out = (float*)d_out;

    // ---- workspace layout ----
    unsigned short* xb0   = (unsigned short*)d_ws;                 // x bf16        [TB][1024]
    unsigned short* xb1   = xb0 + (size_t)TBROWS * HDIM;           // layer0 h bf16 [TB][1024]
    unsigned short* wb0   = xb1 + (size_t)TBROWS * HDIM;           // W_ih0 bf16
    unsigned short* wb1   = wb0 + (size_t)G4H * HDIM;              // W_ih1 bf16
    unsigned short* xproj = wb1 + (size_t)G4H * HDIM;              // x_proj bf16 [TB][4096]
    unsigned short* hhi   = xproj + (size_t)TBROWS * G4H;          // h hi [2][B][H]
    unsigned short* hlo   = hhi + 2 * BATCH * HDIM;                // h lo [2][B][H]
    float* bsum0          = (float*)(hlo + 2 * BATCH * HDIM);      // b_ih+b_hh
    float* bsum1          = bsum0 + G4H;
    unsigned* bar         = (unsigned*)(bsum1 + G4H);              // 1024 step counters, 64B apart

    float* hn0 = out + (size_t)TBROWS * HDIM;
    float* hn1 = hn0 + BATCH * HDIM;
    float* cn0 = hn1 + BATCH * HDIM;
    float* cn1 = cn0 + BATCH * HDIM;

    const unsigned lstm_lds = 32 * HDIM * 2 * 2 + 64 * 33 * 4;  // 139520 B
    static bool attr_set = false;
    if (!attr_set) {
        hipFuncSetAttribute((const void*)k_lstm,
                            hipFuncAttributeMaxDynamicSharedMemorySize, lstm_lds);
        attr_set = true;
    }

    // zero barrier counters (ws is re-poisoned before every call)
    hipMemsetAsync(bar, 0, 2 * T_SEQ * CNT_STRIDE * sizeof(unsigned), stream);

    // conversions
    k_cvt<<<(TBROWS * HDIM / 4 + 255) / 256, 256, 0, stream>>>(x, xb0, TBROWS * HDIM);
    k_cvt<<<(G4H * HDIM / 4 + 255) / 256, 256, 0, stream>>>(Wih0, wb0, G4H * HDIM);
    k_cvt<<<(G4H * HDIM / 4 + 255) / 256, 256, 0, stream>>>(Wih1, wb1, G4H * HDIM);
    k_bias<<<(2 * G4H + 255) / 256, 256, 0, stream>>>(bih0, bhh0, bih1, bhh1, bsum0, bsum1);

    dim3 gg(G4H / 128, TBROWS / 128);   // 32 x 256 blocks

    // layer 0
    k_gemm_bt<<<gg, 256, 0, stream>>>(xb0, wb0, bsum0, xproj, TBROWS, G4H, HDIM);
    {
        const float* whh = Whh0;
        const unsigned short* xp = xproj;
        unsigned short* hh = hhi; unsigned short* hl = hlo;
        unsigned short* ob = xb1;
        float* of = nullptr;
        float* hn = hn0; float* cn = cn0;
        unsigned* bp = bar; int bb = 0;
        void* args[] = {(void*)&whh, (void*)&xp, (void*)&hh, (void*)&hl,
                        (void*)&ob, (void*)&of, (void*)&hn, (void*)&cn,
                        (void*)&bp, (void*)&bb};
        hipLaunchCooperativeKernel((void*)k_lstm, dim3(NBLK), dim3(256), args, lstm_lds, stream);
    }

    // layer 1
    k_gemm_bt<<<gg, 256, 0, stream>>>(xb1, wb1, bsum1, xproj, TBROWS, G4H, HDIM);
    {
        const float* whh = Whh1;
        const unsigned short* xp = xproj;
        unsigned short* hh = hhi; unsigned short* hl = hlo;
        unsigned short* ob = nullptr;
        float* of = out;
        float* hn = hn1; float* cn = cn1;
        unsigned* bp = bar; int bb = T_SEQ;
        void* args[] = {(void*)&whh, (void*)&xp, (void*)&hh, (void*)&hl,
                        (void*)&ob, (void*)&of, (void*)&hn, (void*)&cn,
                        (void*)&bp, (void*)&bb};
        hipLaunchCooperativeKernel((void*)k_lstm, dim3(NBLK), dim3(256), args, lstm_lds, stream);
    }
}